// Round 5
// baseline (695.846 us; speedup 1.0000x reference)
//
#include <hip/hip_runtime.h>
#include <math.h>

// B=4 D=32 N=768 L=192 d_model=128 pred_len=24 in_dim=3
#define NN 768
#define DM 128
#define LL 192
#define BD 128
#define OUT_OFF_A   221184
#define OUT_OFF_GEO 75718656

// ws layout (f32 element offsets):
//  qh : bf16 [98304][128] = 6,291,456 f32 slots   [739328, 7030784)
//  kh : bf16 [98304][128]                         [7030784, 13322240)
//  vT : bf16 [128][128][768]                      [13322240, 19613696)
//  tmat: f32 [98304][128] = 12,582,912            [19613696, 32196608)  peak 128.8 MB
#define WS_CN   16
#define WS_NV1  2048
#define WS_NV2  26624
#define WS_QH   739328
#define WS_KH   7030784
#define WS_VT   13322240
#define WS_T    19613696

constexpr float TEMP_INV    = 20.0f;                  // 1/0.05
constexpr float LARGE_NEG_F = -23.025850929940457f;   // -ln(1e10)
constexpr float QK_SCALE    = 0.08838834764831845f;   // 1/sqrt(128)

typedef unsigned short u16;
typedef u16 u16x8 __attribute__((ext_vector_type(8)));
typedef u16 u16x4 __attribute__((ext_vector_type(4)));
typedef __bf16 bf16x8 __attribute__((ext_vector_type(8)));
typedef float f32x4 __attribute__((ext_vector_type(4)));

__device__ __forceinline__ u16 f2b(float f) {   // f32 -> bf16 RNE
  unsigned u = __builtin_bit_cast(unsigned, f);
  return (u16)((u + 0x7fffu + ((u >> 16) & 1u)) >> 16);
}

// ---------------- kernel 0: min/max over cpan, csta_n ----------------
__global__ __launch_bounds__(256) void k_prep(const float* __restrict__ cpan,
                                              const float* __restrict__ csta,
                                              float* __restrict__ ws) {
  __shared__ float red[4][4];
  int t = threadIdx.x;
  float mnla = 1e30f, mxla = -1e30f, mnlo = 1e30f, mxlo = -1e30f;
  for (int i = t; i < 3072; i += 256) {
    float la = cpan[i * 2 + 0], lo = cpan[i * 2 + 1];
    mnla = fminf(mnla, la); mxla = fmaxf(mxla, la);
    mnlo = fminf(mnlo, lo); mxlo = fmaxf(mxlo, lo);
  }
  for (int off = 1; off < 64; off <<= 1) {
    mnla = fminf(mnla, __shfl_xor(mnla, off));
    mxla = fmaxf(mxla, __shfl_xor(mxla, off));
    mnlo = fminf(mnlo, __shfl_xor(mnlo, off));
    mxlo = fmaxf(mxlo, __shfl_xor(mxlo, off));
  }
  if ((t & 63) == 0) {
    int w = t >> 6;
    red[0][w] = mnla; red[1][w] = mxla; red[2][w] = mnlo; red[3][w] = mxlo;
  }
  __syncthreads();
  mnla = fminf(fminf(red[0][0], red[0][1]), fminf(red[0][2], red[0][3]));
  mxla = fmaxf(fmaxf(red[1][0], red[1][1]), fmaxf(red[1][2], red[1][3]));
  mnlo = fminf(fminf(red[2][0], red[2][1]), fminf(red[2][2], red[2][3]));
  mxlo = fmaxf(fmaxf(red[3][0], red[3][1]), fmaxf(red[3][2], red[3][3]));
  float rla = mxla - mnla + 1e-8f;
  float rlo = mxlo - mnlo + 1e-8f;
  float* cn = ws + WS_CN;
  for (int i = t; i < NN; i += 256) {
    cn[i * 2 + 0] = (csta[i * 2 + 0] - mnla) / rla;
    cn[i * 2 + 1] = (csta[i * 2 + 1] - mnlo) / rlo;
  }
}

// ---------------- kernel 1: node vectors nv1/nv2 ----------------
__global__ __launch_bounds__(64) void k_nodes(const float* __restrict__ cn,
                                              const float* __restrict__ W_sta, const float* __restrict__ b_sta,
                                              const float* __restrict__ W_n1, const float* __restrict__ b_n1,
                                              const float* __restrict__ W_n2, const float* __restrict__ b_n2,
                                              float* __restrict__ nv1, float* __restrict__ nv2) {
  __shared__ float node_c[96];
  int i = blockIdx.x, t = threadIdx.x;
  float c0 = cn[i * 2 + 0], c1 = cn[i * 2 + 1];
  if (t < 32) {
    float nv = c0 * W_sta[t * 2 + 0] + c1 * W_sta[t * 2 + 1] + b_sta[t];
    node_c[t] = sinf(nv);
    node_c[32 + t] = cosf(nv);
    node_c[64 + t] = nv;
  }
  __syncthreads();
  int half = t >> 5, o = t & 31;
  const float* W = half ? W_n2 : W_n1;
  const float* b = half ? b_n2 : b_n1;
  float acc = b[o];
  for (int j = 0; j < 96; ++j) acc = fmaf(node_c[j], W[o * 96 + j], acc);
  acc = fmaxf(acc, 0.0f);
  float ss = acc * acc;
  for (int off = 1; off < 32; off <<= 1) ss += __shfl_xor(ss, off);
  float nrm = fmaxf(sqrtf(ss), 1e-12f);
  (half ? nv2 : nv1)[i * 32 + o] = acc / nrm;
}

// ---------------- kernel 2: geo graph ----------------
__global__ __launch_bounds__(256) void k_geo(const float* __restrict__ nv1, const float* __restrict__ nv2,
                                             const float* __restrict__ cn, const float* __restrict__ dsc_in,
                                             float* __restrict__ geo) {
  int idx = blockIdx.x * 256 + threadIdx.x;
  if (idx >= NN * NN) return;
  int i = idx / NN, j = idx % NN;
  float d1 = 0.f, d2 = 0.f;
  for (int o = 0; o < 32; ++o) {
    d1 = fmaf(nv1[i * 32 + o], nv2[j * 32 + o], d1);
    d2 = fmaf(nv1[j * 32 + o], nv2[i * 32 + o], d2);
  }
  float dla = cn[i * 2] - cn[j * 2], dlo = cn[i * 2 + 1] - cn[j * 2 + 1];
  float dist = sqrtf(dla * dla + dlo * dlo + 1e-8f);
  float x = dsc_in[0];
  float dscale = (1.0f / (1.0f + expf(-x))) * 3.0f;
  float dsim = expf(-dist * dscale);
  geo[idx] = 0.3f * (d1 + d2) + 0.4f * dsim + 0.05f;
}

// ---------------- QKV projection: f32 x staged->bf16, MFMA 128x128, K=192 ----------------
// grid (3, 768): x = z, y = m-tile. z=0: q; z=1: k; z=2: vT [bd][128 col][768 row]
__global__ __launch_bounds__(256) void k_qkv(const float* __restrict__ x,
      const float* __restrict__ Wq, const float* __restrict__ bq,
      const float* __restrict__ Wk, const float* __restrict__ bk,
      const float* __restrict__ Wv, const float* __restrict__ bv,
      u16* __restrict__ qo, u16* __restrict__ ko, u16* __restrict__ vTo) {
  int z = blockIdx.x;
  const float* W    = (z == 0) ? Wq : ((z == 1) ? Wk : Wv);
  const float* bias = (z == 0) ? bq : ((z == 1) ? bk : bv);
  __shared__ u16 xs[128 * 192];
  __shared__ u16 wsd[128 * 192];
  int m0 = blockIdx.y * 128;
  int t = threadIdx.x;
  const float* xg = x + (size_t)m0 * 192;
  for (int i = t; i < 3072; i += 256) {       // 16B chunks: 128 rows x 24
    int row = i / 24, c = i % 24;
    float4 f0 = *(const float4*)(xg + (size_t)row * 192 + c * 8);
    float4 f1 = *(const float4*)(xg + (size_t)row * 192 + c * 8 + 4);
    u16x8 v8 = {f2b(f0.x), f2b(f0.y), f2b(f0.z), f2b(f0.w),
                f2b(f1.x), f2b(f1.y), f2b(f1.z), f2b(f1.w)};
    int byte = (row * 384 + c * 16) ^ ((row & 7) << 4);
    *(u16x8*)((char*)xs + byte) = v8;
    float4 w0 = *(const float4*)(W + row * 192 + c * 8);
    float4 w1 = *(const float4*)(W + row * 192 + c * 8 + 4);
    u16x8 w8 = {f2b(w0.x), f2b(w0.y), f2b(w0.z), f2b(w0.w),
                f2b(w1.x), f2b(w1.y), f2b(w1.z), f2b(w1.w)};
    *(u16x8*)((char*)wsd + byte) = w8;
  }
  __syncthreads();
  int w = t >> 6, l = t & 63, wr = w >> 1, wc = w & 1, lg = l >> 4, lm = l & 15;
  f32x4 acc[4][4] = {};
#pragma unroll
  for (int kk = 0; kk < 6; ++kk) {
    bf16x8 a[4], b[4];
#pragma unroll
    for (int fr = 0; fr < 4; ++fr) {
      int row = wr * 64 + fr * 16 + lm;
      int byte = (row * 384 + kk * 64 + lg * 16) ^ ((row & 7) << 4);
      a[fr] = __builtin_bit_cast(bf16x8, *(const u16x8*)((const char*)xs + byte));
    }
#pragma unroll
    for (int fc = 0; fc < 4; ++fc) {
      int row = wc * 64 + fc * 16 + lm;
      int byte = (row * 384 + kk * 64 + lg * 16) ^ ((row & 7) << 4);
      b[fc] = __builtin_bit_cast(bf16x8, *(const u16x8*)((const char*)wsd + byte));
    }
#pragma unroll
    for (int fr = 0; fr < 4; ++fr)
#pragma unroll
      for (int fc = 0; fc < 4; ++fc)
        acc[fr][fc] = __builtin_amdgcn_mfma_f32_16x16x32_bf16(a[fr], b[fc], acc[fr][fc], 0, 0, 0);
  }
  if (z < 2) {
    u16* out = (z == 0) ? qo : ko;
#pragma unroll
    for (int fr = 0; fr < 4; ++fr)
#pragma unroll
      for (int fc = 0; fc < 4; ++fc) {
        int col = wc * 64 + fc * 16 + lm;
        float bb = bias[col];
#pragma unroll
        for (int r = 0; r < 4; ++r) {
          int row = m0 + wr * 64 + fr * 16 + lg * 4 + r;
          out[(size_t)row * 128 + col] = f2b(acc[fr][fc][r] + bb);
        }
      }
  } else {
    u16* es = xs;   // reuse: 128*132 = 16896 u16
    __syncthreads();
#pragma unroll
    for (int fr = 0; fr < 4; ++fr)
#pragma unroll
      for (int fc = 0; fc < 4; ++fc) {
        int col = wc * 64 + fc * 16 + lm;
        float bb = bias[col];
#pragma unroll
        for (int r = 0; r < 4; ++r) {
          int row = wr * 64 + fr * 16 + lg * 4 + r;
          es[row * 132 + col] = f2b(acc[fr][fc][r] + bb);
        }
      }
    __syncthreads();
    int col = t >> 1, half = t & 1;
    int bd = m0 / NN, ml = m0 % NN;
    u16* dst = vTo + (size_t)bd * 98304 + (size_t)col * NN + ml + half * 64;
#pragma unroll
    for (int i = 0; i < 64; i += 8) {
      u16x8 v8;
#pragma unroll
      for (int j = 0; j < 8; ++j) v8[j] = es[(half * 64 + i + j) * 132 + col];
      *(u16x8*)(dst + i) = v8;
    }
  }
}

// ---------------- fused attention: scores held in registers, single pass ----------------
// grid (12, 128): x = 64-row m-tile, y = bd. 256 threads = 4 waves, wave w owns rows w*16..+16.
// Per lane: acc[6][8] f32x4 = the wave's full 16x768 score strip.
__global__ __launch_bounds__(256, 2) void k_attn(const u16* __restrict__ qh, const u16* __restrict__ kh,
                                                 const u16* __restrict__ vT, const float* __restrict__ geo,
                                                 float* __restrict__ Aout, float* __restrict__ tmat) {
  int m0 = blockIdx.x * 64;
  int bd = blockIdx.y;
  __shared__ u16 kv[128 * 128];     // 32 KB: K chunk, then vT chunk
  __shared__ u16 pb[4][16 * 128];   // 16 KB: per-wave p slice (no cross-wave use)
  int t = threadIdx.x, w = t >> 6, l = t & 63, lm = l & 15, hi = l >> 4;
  const u16* qg = qh + ((size_t)bd * NN + m0) * 128;
  const u16* kg = kh + (size_t)bd * 98304;
  const u16* vg = vT + (size_t)bd * 98304;
  float* Ab = Aout + (size_t)bd * 589824 + (size_t)m0 * NN;
  const float* geob = geo + (size_t)m0 * NN;

  // q fragments straight to regs: rows w*16+lm, k-slice kk*32+hi*8
  bf16x8 qf[4];
#pragma unroll
  for (int kk = 0; kk < 4; ++kk)
    qf[kk] = __builtin_bit_cast(bf16x8,
        *(const u16x8*)(qg + (size_t)(w * 16 + lm) * 128 + kk * 32 + hi * 8));

  f32x4 acc[6][8] = {};

  // ---- QK^T: once. 6 chunks of 128 cols ----
#pragma unroll
  for (int c6 = 0; c6 < 6; ++c6) {
    __syncthreads();
#pragma unroll
    for (int i = 0; i < 8; ++i) {
      int idx = i * 256 + t, row = idx >> 4, c = idx & 15;
      u16x8 v8 = *(const u16x8*)(kg + (size_t)(c6 * 128 + row) * 128 + c * 8);
      int byte = (row * 256 + c * 16) ^ ((row & 7) << 4);
      *(u16x8*)((char*)kv + byte) = v8;
    }
    __syncthreads();
#pragma unroll
    for (int fc = 0; fc < 8; ++fc) {
#pragma unroll
      for (int kk = 0; kk < 4; ++kk) {
        int row = fc * 16 + lm;
        int byte = (row * 256 + kk * 64 + hi * 16) ^ ((row & 7) << 4);
        bf16x8 b = __builtin_bit_cast(bf16x8, *(const u16x8*)((const char*)kv + byte));
        acc[c6][fc] = __builtin_amdgcn_mfma_f32_16x16x32_bf16(qf[kk], b, acc[c6][fc], 0, 0, 0);
      }
    }
  }

  // ---- epilogue in registers: geo*scale + mask, exp, rowsum ----
  float psum[4] = {0.f, 0.f, 0.f, 0.f};
#pragma unroll
  for (int c6 = 0; c6 < 6; ++c6)
#pragma unroll
    for (int fc = 0; fc < 8; ++fc)
#pragma unroll
      for (int r = 0; r < 4; ++r) {
        int rl = w * 16 + hi * 4 + r;
        int col = c6 * 128 + fc * 16 + lm;
        float g = geob[(size_t)rl * NN + col];
        float lgt = (acc[c6][fc][r] * QK_SCALE * g + (g == 0.0f ? LARGE_NEG_F : 0.0f)) * TEMP_INV;
        float u = __expf(fminf(lgt, 85.0f));
        acc[c6][fc][r] = u;
        psum[r] += u;
      }
#pragma unroll
  for (int off = 1; off < 16; off <<= 1)
#pragma unroll
    for (int r = 0; r < 4; ++r) psum[r] += __shfl_xor(psum[r], off);
  float inv[4];
#pragma unroll
  for (int r = 0; r < 4; ++r) inv[r] = 1.0f / psum[r];

  // normalize, write A once, pack p to bf16 (frees acc before PV)
  unsigned pk[6][8][2];
#pragma unroll
  for (int c6 = 0; c6 < 6; ++c6)
#pragma unroll
    for (int fc = 0; fc < 8; ++fc) {
      int rl = w * 16 + hi * 4;
      int col = c6 * 128 + fc * 16 + lm;
      float p0 = acc[c6][fc][0] * inv[0];
      float p1 = acc[c6][fc][1] * inv[1];
      float p2 = acc[c6][fc][2] * inv[2];
      float p3 = acc[c6][fc][3] * inv[3];
      Ab[(size_t)(rl + 0) * NN + col] = p0;
      Ab[(size_t)(rl + 1) * NN + col] = p1;
      Ab[(size_t)(rl + 2) * NN + col] = p2;
      Ab[(size_t)(rl + 3) * NN + col] = p3;
      pk[c6][fc][0] = (unsigned)f2b(p0) | ((unsigned)f2b(p1) << 16);
      pk[c6][fc][1] = (unsigned)f2b(p2) | ((unsigned)f2b(p3) << 16);
    }

  // ---- PV: 6 chunks of 128 n; p via per-wave LDS slice ----
  f32x4 tacc[8] = {};
  u16* pw = pb[w];
#pragma unroll
  for (int c6 = 0; c6 < 6; ++c6) {
    __syncthreads();   // kv readers of previous chunk done
#pragma unroll
    for (int i = 0; i < 8; ++i) {
      int idx = i * 256 + t, row = idx >> 4, c = idx & 15;
      u16x8 v8 = *(const u16x8*)(vg + (size_t)row * NN + c6 * 128 + c * 8);
      int byte = (row * 256 + c * 16) ^ ((row & 7) << 4);
      *(u16x8*)((char*)kv + byte) = v8;
    }
    // write this wave's 16x128 p slice (local rows hi*4+r)
#pragma unroll
    for (int fc = 0; fc < 8; ++fc)
#pragma unroll
      for (int r = 0; r < 4; ++r) {
        int rl = hi * 4 + r;
        int byte = (rl * 256 + (fc * 16 + lm) * 2) ^ ((rl & 7) << 4);
        *(u16*)((char*)pw + byte) = (u16)(pk[c6][fc][r >> 1] >> ((r & 1) * 16));
      }
    __syncthreads();   // kv staged (also orders pw write->read)
    bf16x8 pa[4];
#pragma unroll
    for (int kk = 0; kk < 4; ++kk) {
      int byte = (lm * 256 + kk * 64 + hi * 16) ^ ((lm & 7) << 4);
      pa[kk] = __builtin_bit_cast(bf16x8, *(const u16x8*)((const char*)pw + byte));
    }
#pragma unroll
    for (int fc = 0; fc < 8; ++fc) {
#pragma unroll
      for (int kk = 0; kk < 4; ++kk) {
        int row = fc * 16 + lm;
        int byte = (row * 256 + kk * 64 + hi * 16) ^ ((row & 7) << 4);
        bf16x8 b = __builtin_bit_cast(bf16x8, *(const u16x8*)((const char*)kv + byte));
        tacc[fc] = __builtin_amdgcn_mfma_f32_16x16x32_bf16(pa[kk], b, tacc[fc], 0, 0, 0);
      }
    }
  }
#pragma unroll
  for (int fc = 0; fc < 8; ++fc)
#pragma unroll
    for (int r = 0; r < 4; ++r)
      tmat[((size_t)bd * NN + m0 + w * 16 + hi * 4 + r) * 128 + fc * 16 + lm] = tacc[fc][r];
}

// ---------------- final: fc1 + reshape + fc2 ----------------
__global__ __launch_bounds__(256) void k_final(const float* __restrict__ tmat, const float* __restrict__ W_fc1,
                                               const float* __restrict__ b_fc1, const float* __restrict__ W_fc2,
                                               const float* __restrict__ b_fc2, float* __restrict__ out) {
  int b = blockIdx.x / NN, n = blockIdx.x % NN;
  __shared__ float tl[32 * 128];
  __shared__ float w1[24 * 128];
  __shared__ float o1[32 * 24];
  int t = threadIdx.x;
  for (int idx = t; idx < 4096; idx += 256) {
    int d = idx >> 7, j = idx & 127;
    tl[idx] = tmat[((size_t)(b * 32 + d) * NN + n) * DM + j];
  }
  for (int idx = t; idx < 3072; idx += 256) w1[idx] = W_fc1[idx];
  __syncthreads();
  for (int task = t; task < 768; task += 256) {
    int d = task / 24, pp = task % 24;
    float acc = b_fc1[pp];
#pragma unroll 8
    for (int j = 0; j < 128; ++j) acc = fmaf(tl[d * 128 + j], w1[pp * 128 + j], acc);
    o1[task] = acc;
  }
  __syncthreads();
  if (t < 72) {
    int c = t / 24, pp = t % 24;
    float acc = b_fc2[c];
#pragma unroll
    for (int d = 0; d < 32; ++d) acc = fmaf(W_fc2[c * 32 + d], o1[d * 24 + pp], acc);
    out[(((size_t)b * 3 + c) * NN + n) * 24 + pp] = acc;
  }
}

extern "C" void kernel_launch(void* const* d_in, const int* in_sizes, int n_in,
                              void* d_out, int out_size, void* d_ws, size_t ws_size,
                              hipStream_t stream) {
  (void)in_sizes; (void)n_in; (void)out_size; (void)ws_size;
  const float* x     = (const float*)d_in[1];
  const float* csta  = (const float*)d_in[2];
  const float* cpan  = (const float*)d_in[3];
  const float* Wq    = (const float*)d_in[4];
  const float* bq    = (const float*)d_in[5];
  const float* Wk    = (const float*)d_in[6];
  const float* bk    = (const float*)d_in[7];
  const float* Wv    = (const float*)d_in[8];
  const float* bv    = (const float*)d_in[9];
  const float* W_sta = (const float*)d_in[10];
  const float* b_sta = (const float*)d_in[11];
  const float* W_n1  = (const float*)d_in[12];
  const float* b_n1  = (const float*)d_in[13];
  const float* W_n2  = (const float*)d_in[14];
  const float* b_n2  = (const float*)d_in[15];
  const float* dsc   = (const float*)d_in[16];
  const float* W_fc1 = (const float*)d_in[17];
  const float* b_fc1 = (const float*)d_in[18];
  const float* W_fc2 = (const float*)d_in[19];
  const float* b_fc2 = (const float*)d_in[20];

  float* out  = (float*)d_out;
  float* Aout = out + OUT_OFF_A;
  float* geo  = out + OUT_OFF_GEO;

  float* ws   = (float*)d_ws;
  float* cn   = ws + WS_CN;
  float* nv1  = ws + WS_NV1;
  float* nv2  = ws + WS_NV2;
  u16*   qh   = (u16*)(ws + WS_QH);
  u16*   kh   = (u16*)(ws + WS_KH);
  u16*   vT   = (u16*)(ws + WS_VT);
  float* tmat = ws + WS_T;

  k_prep<<<1, 256, 0, stream>>>(cpan, csta, ws);
  k_nodes<<<768, 64, 0, stream>>>(cn, W_sta, b_sta, W_n1, b_n1, W_n2, b_n2, nv1, nv2);
  k_geo<<<(NN * NN + 255) / 256, 256, 0, stream>>>(nv1, nv2, cn, dsc, geo);

  k_qkv<<<dim3(3, 768), 256, 0, stream>>>(x, Wq, bq, Wk, bk, Wv, bv, qh, kh, vT);
  k_attn<<<dim3(12, BD), 256, 0, stream>>>(qh, kh, vT, geo, Aout, tmat);
  k_final<<<4 * NN, 256, 0, stream>>>(tmat, W_fc1, b_fc1, W_fc2, b_fc2, out);
}